// Round 1
// baseline (1061.312 us; speedup 1.0000x reference)
//
#include <hip/hip_runtime.h>

#define NNODES 100000
#define NEDGES 1600000
#define NSUB   1000
#define MSUB   64
#define MHID   128
#define CAP    64   // max in-degree bucket capacity (Poisson(16): P(>=64) ~ 1e-20)

// ---------------- graph preprocessing ----------------

__global__ void k_zero(float* deg, int* cnt, float* stats) {
    int i = blockIdx.x * blockDim.x + threadIdx.x;
    if (i < NNODES) { deg[i] = 0.0f; cnt[i] = 0; }
    if (i < 256)    { stats[i] = 0.0f; }
}

__global__ void k_deg(const int* __restrict__ dst, const float* __restrict__ ew,
                      float* __restrict__ deg) {
    int e = blockIdx.x * blockDim.x + threadIdx.x;
    if (e < NEDGES) atomicAdd(&deg[dst[e]], ew[e]);
}

__global__ void k_dinv(float* dinv, float* self_norm) {
    int n = blockIdx.x * blockDim.x + threadIdx.x;
    if (n < NNODES) {
        float d = rsqrtf(dinv[n] + 1.0f);
        dinv[n] = d;
        self_norm[n] = d * d;
    }
}

__global__ void k_fill(const int* __restrict__ src, const int* __restrict__ dst,
                       const float* __restrict__ ew, const float* __restrict__ dinv,
                       int* __restrict__ cnt, int* __restrict__ bsrc,
                       float* __restrict__ bw) {
    int e = blockIdx.x * blockDim.x + threadIdx.x;
    if (e >= NEDGES) return;
    int s = src[e], d = dst[e];
    float nor = dinv[s] * ew[e] * dinv[d];
    int pos = atomicAdd(&cnt[d], 1);
    if (pos < CAP) { bsrc[d * CAP + pos] = s; bw[d * CAP + pos] = nor; }
}

// ---------------- GEMM: [200000 x 64] @ [64 x 64] ----------------
// One row per lane; W staged in LDS, read as wave-uniform float4 broadcasts.
// TR=true applies per-column affine (GraphNorm) + ReLU to the input row.

template <bool TR>
__global__ __launch_bounds__(256) void k_gemm(const float* __restrict__ X,
                                              const float* __restrict__ Wg,
                                              float* __restrict__ Y,
                                              const float* __restrict__ Acoef,
                                              const float* __restrict__ Bcoef) {
    __shared__ __align__(16) float Wl[64 * 64];
    int t = threadIdx.x;
    #pragma unroll
    for (int i = 0; i < 16; i++) Wl[i * 256 + t] = Wg[i * 256 + t];
    __syncthreads();

    int wid  = blockIdx.x * 4 + (t >> 6);  // wave id
    int lane = t & 63;
    int c = wid & 1;        // channel (wave-uniform)
    int g = wid >> 1;       // node group
    int n = g * 64 + lane;  // node for this lane
    if (n >= NNODES) return;
    int row = n * 2 + c;

    const float* xp = X + (size_t)row * 64;
    float4 xr[16];
    #pragma unroll
    for (int q = 0; q < 16; q++) xr[q] = ((const float4*)xp)[q];

    if (TR) {
        const float* A = Acoef + c * 64;
        const float* B = Bcoef + c * 64;
        #pragma unroll
        for (int q = 0; q < 16; q++) {
            float4 a = ((const float4*)A)[q];
            float4 b = ((const float4*)B)[q];
            xr[q].x = fmaxf(a.x * xr[q].x + b.x, 0.0f);
            xr[q].y = fmaxf(a.y * xr[q].y + b.y, 0.0f);
            xr[q].z = fmaxf(a.z * xr[q].z + b.z, 0.0f);
            xr[q].w = fmaxf(a.w * xr[q].w + b.w, 0.0f);
        }
    }

    float* yp = Y + (size_t)row * 64;
    for (int jg = 0; jg < 16; jg++) {
        float4 acc = make_float4(0.f, 0.f, 0.f, 0.f);
        const float* xs = (const float*)xr;
        #pragma unroll
        for (int k = 0; k < 64; k++) {
            float xv = xs[k];
            float4 w4 = ((const float4*)(Wl + k * 64))[jg];
            acc.x += xv * w4.x; acc.y += xv * w4.y;
            acc.z += xv * w4.z; acc.w += xv * w4.w;
        }
        ((float4*)yp)[jg] = acc;
    }
}

// ---------------- pull-style GCN aggregation ----------------
// wave per (node, channel); lane = feature. No atomics.

__global__ __launch_bounds__(256) void k_prop(const float* __restrict__ hw,
                                              const float* __restrict__ bias,
                                              const float* __restrict__ self_norm,
                                              const int* __restrict__ cnt,
                                              const int* __restrict__ bsrc,
                                              const float* __restrict__ bw,
                                              float* __restrict__ agg) {
    int t = threadIdx.x;
    int wid  = blockIdx.x * 4 + (t >> 6);   // [0, 200000)
    int lane = t & 63;
    int n = wid >> 1;
    int c = wid & 1;
    if (n >= NNODES) return;

    float acc = bias[lane] + self_norm[n] * hw[(n * 2 + c) * 64 + lane];
    int cn = cnt[n];
    if (cn > CAP) cn = CAP;
    const int*   bs  = bsrc + n * CAP;
    const float* bwp = bw   + n * CAP;
    for (int p = 0; p < cn; p++) {
        int s   = bs[p];
        float w = bwp[p];
        acc += w * hw[(s * 2 + c) * 64 + lane];
    }
    agg[(n * 2 + c) * 64 + lane] = acc;
}

// ---------------- GraphNorm stats (sum, sumsq per column) ----------------

__global__ __launch_bounds__(256) void k_stats(const float* __restrict__ agg,
                                               float* __restrict__ stats) {
    int t = threadIdx.x;
    int col  = t & 127;
    int half = t >> 7;
    float s = 0.f, s2 = 0.f;
    for (int r = blockIdx.x * 2 + half; r < NNODES; r += gridDim.x * 2) {
        float v = agg[r * 128 + col];
        s += v; s2 += v * v;
    }
    atomicAdd(&stats[col], s);
    atomicAdd(&stats[128 + col], s2);
}

__global__ void k_coef(float* stats, const float* __restrict__ gn_w,
                       const float* __restrict__ gn_b, const float* __restrict__ gn_ms) {
    int col = threadIdx.x;  // 128
    float inv_n = 1.0f / (float)NNODES;
    float mean = stats[col] * inv_n;
    float eh2  = stats[128 + col] * inv_n;
    int f = col & 63;
    float ms = gn_ms[f];
    // var of (h - ms*mean) = E[h^2] - 2*ms*mean*E[h] + ms^2*mean^2
    float var = eh2 - 2.0f * ms * mean * mean + ms * ms * mean * mean;
    float A = gn_w[f] * rsqrtf(var + 1e-5f);
    stats[256 + col] = A;
    stats[384 + col] = gn_b[f] - A * ms * mean;
}

// ---------------- subgraph pooling (channel mean + member sum) ----------------

__global__ __launch_bounds__(64) void k_pool(const float* __restrict__ agg,
                                             const int* __restrict__ subg,
                                             float* __restrict__ pooled) {
    int s = blockIdx.x, j = threadIdx.x;
    const int* idx = subg + s * 64;
    float acc = 0.f;
    for (int m = 0; m < MSUB; m++) {
        int n = idx[m];
        acc += 0.5f * (agg[n * 128 + j] + agg[n * 128 + 64 + j]);
    }
    pooled[s * 64 + j] = acc;
}

// ---------------- MLP head ----------------

__global__ __launch_bounds__(128) void k_mlp(const float* __restrict__ pooled,
                                             const float* __restrict__ mW1,
                                             const float* __restrict__ mb1,
                                             const float* __restrict__ mW2,
                                             const float* __restrict__ mb2,
                                             float* __restrict__ out) {
    __shared__ float pl[64];
    __shared__ float red[128];
    int s = blockIdx.x, t = threadIdx.x;
    if (t < 64) pl[t] = pooled[s * 64 + t];
    __syncthreads();
    float h = mb1[t];
    #pragma unroll
    for (int k = 0; k < 64; k++) h += pl[k] * mW1[k * 128 + t];
    h = fmaxf(h, 0.0f);
    red[t] = h * mW2[t];
    __syncthreads();
    for (int off = 64; off > 0; off >>= 1) {
        if (t < off) red[t] += red[t + off];
        __syncthreads();
    }
    if (t == 0) out[s] = red[0] + mb2[0];
}

// ---------------- launcher ----------------

extern "C" void kernel_launch(void* const* d_in, const int* in_sizes, int n_in,
                              void* d_out, int out_size, void* d_ws, size_t ws_size,
                              hipStream_t stream) {
    const float* x     = (const float*)d_in[0];   // [N, 2, 64]
    const int*   ei    = (const int*)d_in[1];     // [2, E]
    const float* ew    = (const float*)d_in[2];   // [E]
    const int*   subg  = (const int*)d_in[3];     // [S, 64]
    const float* W1    = (const float*)d_in[4];
    const float* b1    = (const float*)d_in[5];
    const float* gn_w  = (const float*)d_in[6];
    const float* gn_b  = (const float*)d_in[7];
    const float* gn_ms = (const float*)d_in[8];
    const float* W2    = (const float*)d_in[9];
    const float* b2    = (const float*)d_in[10];
    const float* mW1   = (const float*)d_in[11];
    const float* mb1   = (const float*)d_in[12];
    const float* mW2   = (const float*)d_in[13];
    const float* mb2   = (const float*)d_in[14];
    float* out = (float*)d_out;

    char* w = (char*)d_ws;
    size_t off = 0;
    auto alloc = [&](size_t bytes) {
        void* p = w + off;
        off = (off + bytes + 255) & ~(size_t)255;
        return p;
    };
    float* dinv      = (float*)alloc((size_t)NNODES * 4);          // deg -> dinv in place
    float* self_norm = (float*)alloc((size_t)NNODES * 4);
    int*   cnt       = (int*)  alloc((size_t)NNODES * 4);
    int*   bsrc      = (int*)  alloc((size_t)NNODES * CAP * 4);    // 25.6 MB
    float* bw        = (float*)alloc((size_t)NNODES * CAP * 4);    // 25.6 MB
    float* hw        = (float*)alloc((size_t)NNODES * 128 * 4);    // 51.2 MB
    float* agg       = (float*)alloc((size_t)NNODES * 128 * 4);    // 51.2 MB
    float* stats     = (float*)alloc(512 * 4);   // [sum128 | sumsq128 | A128 | B128]
    float* pooled    = (float*)alloc((size_t)NSUB * 64 * 4);

    const int* src = ei;
    const int* dst = ei + NEDGES;

    // preprocessing
    k_zero<<<(NNODES + 255) / 256, 256, 0, stream>>>(dinv, cnt, stats);
    k_deg <<<(NEDGES + 255) / 256, 256, 0, stream>>>(dst, ew, dinv);
    k_dinv<<<(NNODES + 255) / 256, 256, 0, stream>>>(dinv, self_norm);
    k_fill<<<(NEDGES + 255) / 256, 256, 0, stream>>>(src, dst, ew, dinv, cnt, bsrc, bw);

    // layer 1
    k_gemm<false><<<782, 256, 0, stream>>>(x, W1, hw, nullptr, nullptr);
    k_prop<<<50000, 256, 0, stream>>>(hw, b1, self_norm, cnt, bsrc, bw, agg);

    // GraphNorm coefficients
    k_stats<<<256, 256, 0, stream>>>(agg, stats);
    k_coef<<<1, 128, 0, stream>>>(stats, gn_w, gn_b, gn_ms);

    // layer 2 (GraphNorm+ReLU fused into GEMM2 input)
    k_gemm<true><<<782, 256, 0, stream>>>(agg, W2, hw, stats + 256, stats + 384);
    k_prop<<<50000, 256, 0, stream>>>(hw, b2, self_norm, cnt, bsrc, bw, agg);

    // pooling + MLP head
    k_pool<<<NSUB, 64, 0, stream>>>(agg, subg, pooled);
    k_mlp <<<NSUB, 128, 0, stream>>>(pooled, mW1, mb1, mW2, mb2, out);
}

// Round 2
// 707.309 us; speedup vs baseline: 1.5005x; 1.5005x over previous
//
#include <hip/hip_runtime.h>

#define NNODES 100000
#define NEDGES 1600000
#define NSUB   1000
#define MSUB   64
#define MHID   128
#define CAP    64   // max in-degree bucket capacity (Poisson(16): P(>=64) ~ 1e-20)

// ---------------- graph preprocessing ----------------

__global__ void k_zero(float* deg, int* cnt, float* stats) {
    int i = blockIdx.x * blockDim.x + threadIdx.x;
    if (i < NNODES) { deg[i] = 0.0f; cnt[i] = 0; }
    if (i < 256)    { stats[i] = 0.0f; }
}

__global__ void k_deg(const int* __restrict__ dst, const float* __restrict__ ew,
                      float* __restrict__ deg) {
    int e = blockIdx.x * blockDim.x + threadIdx.x;
    if (e < NEDGES) atomicAdd(&deg[dst[e]], ew[e]);
}

__global__ void k_dinv(float* dinv, float* self_norm) {
    int n = blockIdx.x * blockDim.x + threadIdx.x;
    if (n < NNODES) {
        float d = rsqrtf(dinv[n] + 1.0f);
        dinv[n] = d;
        self_norm[n] = d * d;
    }
}

// pairs[d*CAP + pos] = (src, bitcast(norm)) — single 8 B scatter per edge
__global__ void k_fill(const int* __restrict__ src, const int* __restrict__ dst,
                       const float* __restrict__ ew, const float* __restrict__ dinv,
                       int* __restrict__ cnt, int2* __restrict__ pairs) {
    int e = blockIdx.x * blockDim.x + threadIdx.x;
    if (e >= NEDGES) return;
    int s = src[e], d = dst[e];
    float nor = dinv[s] * ew[e] * dinv[d];
    int pos = atomicAdd(&cnt[d], 1);
    if (pos < CAP) pairs[(size_t)d * CAP + pos] = make_int2(s, __float_as_int(nor));
}

// pad each bucket to a multiple of 8 with (n, 0.0f) so k_prop's loop is branch-free
__global__ void k_pad(const int* __restrict__ cnt, int2* __restrict__ pairs) {
    int n = blockIdx.x * blockDim.x + threadIdx.x;
    if (n >= NNODES) return;
    int c = cnt[n]; if (c > CAP) c = CAP;
    int c8 = (c + 7) & ~7;
    int2 dummy = make_int2(n, 0);   // weight bits 0 == 0.0f
    for (int p = c; p < c8; p++) pairs[(size_t)n * CAP + p] = dummy;
}

// ---------------- GEMM: [200000 x 64] @ [64 x 64] ----------------

template <bool TR>
__global__ __launch_bounds__(256) void k_gemm(const float* __restrict__ X,
                                              const float* __restrict__ Wg,
                                              float* __restrict__ Y,
                                              const float* __restrict__ Acoef,
                                              const float* __restrict__ Bcoef) {
    __shared__ __align__(16) float Wl[64 * 64];
    int t = threadIdx.x;
    #pragma unroll
    for (int i = 0; i < 16; i++) Wl[i * 256 + t] = Wg[i * 256 + t];
    __syncthreads();

    int wid  = blockIdx.x * 4 + (t >> 6);
    int lane = t & 63;
    int c = wid & 1;
    int g = wid >> 1;
    int n = g * 64 + lane;
    if (n >= NNODES) return;
    int row = n * 2 + c;

    const float* xp = X + (size_t)row * 64;
    float4 xr[16];
    #pragma unroll
    for (int q = 0; q < 16; q++) xr[q] = ((const float4*)xp)[q];

    if (TR) {
        const float* A = Acoef + c * 64;
        const float* B = Bcoef + c * 64;
        #pragma unroll
        for (int q = 0; q < 16; q++) {
            float4 a = ((const float4*)A)[q];
            float4 b = ((const float4*)B)[q];
            xr[q].x = fmaxf(a.x * xr[q].x + b.x, 0.0f);
            xr[q].y = fmaxf(a.y * xr[q].y + b.y, 0.0f);
            xr[q].z = fmaxf(a.z * xr[q].z + b.z, 0.0f);
            xr[q].w = fmaxf(a.w * xr[q].w + b.w, 0.0f);
        }
    }

    float* yp = Y + (size_t)row * 64;
    for (int jg = 0; jg < 16; jg++) {
        float4 acc = make_float4(0.f, 0.f, 0.f, 0.f);
        const float* xs = (const float*)xr;
        #pragma unroll
        for (int k = 0; k < 64; k++) {
            float xv = xs[k];
            float4 w4 = ((const float4*)(Wl + k * 64))[jg];
            acc.x += xv * w4.x; acc.y += xv * w4.y;
            acc.z += xv * w4.z; acc.w += xv * w4.w;
        }
        ((float4*)yp)[jg] = acc;
    }
}

// ---------------- pull-style GCN aggregation ----------------
// One wave per NODE (both channels at once). Lane l covers flat feature
// offsets [2l, 2l+1] of the node's 128-float block -> one dwordx2 gather per
// neighbor covers both channels. Index lists are wave-uniform (s_load).
// Buckets are padded to a multiple of 8 -> branch-free batch-8 inner loop
// with 8 independent gathers in flight.

__global__ __launch_bounds__(256) void k_prop(const float* __restrict__ hw,
                                              const float* __restrict__ bias,
                                              const float* __restrict__ self_norm,
                                              const int* __restrict__ cnt,
                                              const int2* __restrict__ pairs,
                                              float* __restrict__ agg) {
    int t = threadIdx.x;
    int lane = t & 63;
    int n = __builtin_amdgcn_readfirstlane(blockIdx.x * 4 + (t >> 6));
    if (n >= NNODES) return;

    int f = lane * 2;            // flat offset in [0,128), even
    int feat = f & 63;           // feature within channel (feat, feat+1 same channel)

    float2 bv = *(const float2*)(bias + feat);
    float sn = self_norm[n];
    const float* hb = hw + (size_t)n * 128;
    float2 self = *(const float2*)(hb + f);
    float acc0 = bv.x + sn * self.x;
    float acc1 = bv.y + sn * self.y;

    int cn = cnt[n]; if (cn > CAP) cn = CAP;
    int c8 = (cn + 7) & ~7;
    const int2* pp = pairs + (size_t)n * CAP;

    for (int p = 0; p < c8; p += 8) {
        int2 e0 = pp[p + 0], e1 = pp[p + 1], e2 = pp[p + 2], e3 = pp[p + 3];
        int2 e4 = pp[p + 4], e5 = pp[p + 5], e6 = pp[p + 6], e7 = pp[p + 7];
        float2 h0 = *(const float2*)(hw + (size_t)e0.x * 128 + f);
        float2 h1 = *(const float2*)(hw + (size_t)e1.x * 128 + f);
        float2 h2 = *(const float2*)(hw + (size_t)e2.x * 128 + f);
        float2 h3 = *(const float2*)(hw + (size_t)e3.x * 128 + f);
        float2 h4 = *(const float2*)(hw + (size_t)e4.x * 128 + f);
        float2 h5 = *(const float2*)(hw + (size_t)e5.x * 128 + f);
        float2 h6 = *(const float2*)(hw + (size_t)e6.x * 128 + f);
        float2 h7 = *(const float2*)(hw + (size_t)e7.x * 128 + f);
        float w0 = __int_as_float(e0.y), w1 = __int_as_float(e1.y);
        float w2 = __int_as_float(e2.y), w3 = __int_as_float(e3.y);
        float w4 = __int_as_float(e4.y), w5 = __int_as_float(e5.y);
        float w6 = __int_as_float(e6.y), w7 = __int_as_float(e7.y);
        acc0 += w0 * h0.x; acc1 += w0 * h0.y;
        acc0 += w1 * h1.x; acc1 += w1 * h1.y;
        acc0 += w2 * h2.x; acc1 += w2 * h2.y;
        acc0 += w3 * h3.x; acc1 += w3 * h3.y;
        acc0 += w4 * h4.x; acc1 += w4 * h4.y;
        acc0 += w5 * h5.x; acc1 += w5 * h5.y;
        acc0 += w6 * h6.x; acc1 += w6 * h6.y;
        acc0 += w7 * h7.x; acc1 += w7 * h7.y;
    }

    *(float2*)(agg + (size_t)n * 128 + f) = make_float2(acc0, acc1);
}

// ---------------- GraphNorm stats (sum, sumsq per column) ----------------

__global__ __launch_bounds__(256) void k_stats(const float* __restrict__ agg,
                                               float* __restrict__ stats) {
    int t = threadIdx.x;
    int col  = t & 127;
    int half = t >> 7;
    float s = 0.f, s2 = 0.f;
    for (int r = blockIdx.x * 2 + half; r < NNODES; r += gridDim.x * 2) {
        float v = agg[r * 128 + col];
        s += v; s2 += v * v;
    }
    atomicAdd(&stats[col], s);
    atomicAdd(&stats[128 + col], s2);
}

__global__ void k_coef(float* stats, const float* __restrict__ gn_w,
                       const float* __restrict__ gn_b, const float* __restrict__ gn_ms) {
    int col = threadIdx.x;  // 128
    float inv_n = 1.0f / (float)NNODES;
    float mean = stats[col] * inv_n;
    float eh2  = stats[128 + col] * inv_n;
    int f = col & 63;
    float ms = gn_ms[f];
    float var = eh2 - 2.0f * ms * mean * mean + ms * ms * mean * mean;
    float A = gn_w[f] * rsqrtf(var + 1e-5f);
    stats[256 + col] = A;
    stats[384 + col] = gn_b[f] - A * ms * mean;
}

// ---------------- subgraph pooling ----------------

__global__ __launch_bounds__(64) void k_pool(const float* __restrict__ agg,
                                             const int* __restrict__ subg,
                                             float* __restrict__ pooled) {
    int s = blockIdx.x, j = threadIdx.x;
    const int* idx = subg + s * 64;
    float acc = 0.f;
    for (int m = 0; m < MSUB; m++) {
        int n = idx[m];
        acc += 0.5f * (agg[n * 128 + j] + agg[n * 128 + 64 + j]);
    }
    pooled[s * 64 + j] = acc;
}

// ---------------- MLP head ----------------

__global__ __launch_bounds__(128) void k_mlp(const float* __restrict__ pooled,
                                             const float* __restrict__ mW1,
                                             const float* __restrict__ mb1,
                                             const float* __restrict__ mW2,
                                             const float* __restrict__ mb2,
                                             float* __restrict__ out) {
    __shared__ float pl[64];
    __shared__ float red[128];
    int s = blockIdx.x, t = threadIdx.x;
    if (t < 64) pl[t] = pooled[s * 64 + t];
    __syncthreads();
    float h = mb1[t];
    #pragma unroll
    for (int k = 0; k < 64; k++) h += pl[k] * mW1[k * 128 + t];
    h = fmaxf(h, 0.0f);
    red[t] = h * mW2[t];
    __syncthreads();
    for (int off = 64; off > 0; off >>= 1) {
        if (t < off) red[t] += red[t + off];
        __syncthreads();
    }
    if (t == 0) out[s] = red[0] + mb2[0];
}

// ---------------- launcher ----------------

extern "C" void kernel_launch(void* const* d_in, const int* in_sizes, int n_in,
                              void* d_out, int out_size, void* d_ws, size_t ws_size,
                              hipStream_t stream) {
    const float* x     = (const float*)d_in[0];
    const int*   ei    = (const int*)d_in[1];
    const float* ew    = (const float*)d_in[2];
    const int*   subg  = (const int*)d_in[3];
    const float* W1    = (const float*)d_in[4];
    const float* b1    = (const float*)d_in[5];
    const float* gn_w  = (const float*)d_in[6];
    const float* gn_b  = (const float*)d_in[7];
    const float* gn_ms = (const float*)d_in[8];
    const float* W2    = (const float*)d_in[9];
    const float* b2    = (const float*)d_in[10];
    const float* mW1   = (const float*)d_in[11];
    const float* mb1   = (const float*)d_in[12];
    const float* mW2   = (const float*)d_in[13];
    const float* mb2   = (const float*)d_in[14];
    float* out = (float*)d_out;

    char* w = (char*)d_ws;
    size_t off = 0;
    auto alloc = [&](size_t bytes) {
        void* p = w + off;
        off = (off + bytes + 255) & ~(size_t)255;
        return p;
    };
    float* dinv      = (float*)alloc((size_t)NNODES * 4);
    float* self_norm = (float*)alloc((size_t)NNODES * 4);
    int*   cnt       = (int*)  alloc((size_t)NNODES * 4);
    int2*  pairs     = (int2*) alloc((size_t)NNODES * CAP * 8);    // 51.2 MB
    float* hw        = (float*)alloc((size_t)NNODES * 128 * 4);    // 51.2 MB
    float* agg       = (float*)alloc((size_t)NNODES * 128 * 4);    // 51.2 MB
    float* stats     = (float*)alloc(512 * 4);
    float* pooled    = (float*)alloc((size_t)NSUB * 64 * 4);

    const int* src = ei;
    const int* dst = ei + NEDGES;

    // preprocessing
    k_zero<<<(NNODES + 255) / 256, 256, 0, stream>>>(dinv, cnt, stats);
    k_deg <<<(NEDGES + 255) / 256, 256, 0, stream>>>(dst, ew, dinv);
    k_dinv<<<(NNODES + 255) / 256, 256, 0, stream>>>(dinv, self_norm);
    k_fill<<<(NEDGES + 255) / 256, 256, 0, stream>>>(src, dst, ew, dinv, cnt, pairs);
    k_pad <<<(NNODES + 255) / 256, 256, 0, stream>>>(cnt, pairs);

    // layer 1
    k_gemm<false><<<782, 256, 0, stream>>>(x, W1, hw, nullptr, nullptr);
    k_prop<<<25000, 256, 0, stream>>>(hw, b1, self_norm, cnt, pairs, agg);

    // GraphNorm coefficients
    k_stats<<<256, 256, 0, stream>>>(agg, stats);
    k_coef<<<1, 128, 0, stream>>>(stats, gn_w, gn_b, gn_ms);

    // layer 2 (GraphNorm+ReLU fused into GEMM2 input)
    k_gemm<true><<<782, 256, 0, stream>>>(agg, W2, hw, stats + 256, stats + 384);
    k_prop<<<25000, 256, 0, stream>>>(hw, b2, self_norm, cnt, pairs, agg);

    // pooling + MLP head
    k_pool<<<NSUB, 64, 0, stream>>>(agg, subg, pooled);
    k_mlp <<<NSUB, 128, 0, stream>>>(pooled, mW1, mb1, mW2, mb2, out);
}

// Round 3
// 604.774 us; speedup vs baseline: 1.7549x; 1.1695x over previous
//
#include <hip/hip_runtime.h>
#include <hip/hip_fp16.h>

#define NNODES 100000
#define NEDGES 1600000
#define NSUB   1000
#define MSUB   64
#define MHID   128
#define CAP    64   // max in-degree bucket capacity (Poisson(16): P(>=64) ~ 1e-20)

// ---------------- graph preprocessing ----------------

// one edge pass: degree accumulation + bucket scatter (raw ew, normalized later)
__global__ void k_fill(const int* __restrict__ src, const int* __restrict__ dst,
                       const float* __restrict__ ew,
                       float* __restrict__ deg, int* __restrict__ cnt,
                       int2* __restrict__ pairs) {
    int e = blockIdx.x * blockDim.x + threadIdx.x;
    if (e >= NEDGES) return;
    int s = src[e], d = dst[e];
    float w = ew[e];
    atomicAdd(&deg[d], w);
    int pos = atomicAdd(&cnt[d], 1);
    if (pos < CAP) pairs[(size_t)d * CAP + pos] = make_int2(s, __float_as_int(w));
}

__global__ void k_dinv(float* dinv, float* self_norm) {
    int n = blockIdx.x * blockDim.x + threadIdx.x;
    if (n < NNODES) {
        float d = rsqrtf(dinv[n] + 1.0f);
        dinv[n] = d;
        self_norm[n] = d * d;
    }
}

// wave per node: normalize bucket weights (w *= dinv[s]*dinv[d]) and pad the
// bucket to a multiple of 16 with (n, 0.0f) dummies. Coalesced 8 B/lane.
__global__ __launch_bounds__(256) void k_norm(const float* __restrict__ dinv,
                                              const int* __restrict__ cnt,
                                              int2* __restrict__ pairs) {
    int t = threadIdx.x, lane = t & 63;
    int n = blockIdx.x * 4 + (t >> 6);
    if (n >= NNODES) return;
    int cn = cnt[n]; if (cn > CAP) cn = CAP;
    int c16 = (cn + 15) & ~15;
    float dd = dinv[n];
    if (lane < c16) {
        int2 outp;
        if (lane < cn) {
            int2 pr = pairs[(size_t)n * CAP + lane];
            float w = __int_as_float(pr.y) * dd * dinv[pr.x];
            outp = make_int2(pr.x, __float_as_int(w));
        } else {
            outp = make_int2(n, 0);   // weight bits 0 == 0.0f
        }
        pairs[(size_t)n * CAP + lane] = outp;
    }
}

// ---------------- GEMM: [200000 x 64] @ [64 x 64], fp32 in, fp16 out --------

template <bool TR>
__global__ __launch_bounds__(256) void k_gemm(const float* __restrict__ X,
                                              const float* __restrict__ Wg,
                                              __half* __restrict__ Y,
                                              const float* __restrict__ Acoef,
                                              const float* __restrict__ Bcoef) {
    __shared__ __align__(16) float Wl[64 * 64];
    int t = threadIdx.x;
    #pragma unroll
    for (int i = 0; i < 16; i++) Wl[i * 256 + t] = Wg[i * 256 + t];
    __syncthreads();

    int wid  = blockIdx.x * 4 + (t >> 6);
    int lane = t & 63;
    int c = wid & 1;
    int g = wid >> 1;
    int n = g * 64 + lane;
    if (n >= NNODES) return;
    int row = n * 2 + c;

    const float* xp = X + (size_t)row * 64;
    float4 xr[16];
    #pragma unroll
    for (int q = 0; q < 16; q++) xr[q] = ((const float4*)xp)[q];

    if (TR) {
        const float* A = Acoef + c * 64;
        const float* B = Bcoef + c * 64;
        #pragma unroll
        for (int q = 0; q < 16; q++) {
            float4 a = ((const float4*)A)[q];
            float4 b = ((const float4*)B)[q];
            xr[q].x = fmaxf(a.x * xr[q].x + b.x, 0.0f);
            xr[q].y = fmaxf(a.y * xr[q].y + b.y, 0.0f);
            xr[q].z = fmaxf(a.z * xr[q].z + b.z, 0.0f);
            xr[q].w = fmaxf(a.w * xr[q].w + b.w, 0.0f);
        }
    }

    __half* yp = Y + (size_t)row * 64;
    for (int jg = 0; jg < 16; jg++) {
        float4 acc = make_float4(0.f, 0.f, 0.f, 0.f);
        const float* xs = (const float*)xr;
        #pragma unroll
        for (int k = 0; k < 64; k++) {
            float xv = xs[k];
            float4 w4 = ((const float4*)(Wl + k * 64))[jg];
            acc.x += xv * w4.x; acc.y += xv * w4.y;
            acc.z += xv * w4.z; acc.w += xv * w4.w;
        }
        union { __half2 h2[2]; uint2 u2; } cv;
        cv.h2[0] = __floats2half2_rn(acc.x, acc.y);
        cv.h2[1] = __floats2half2_rn(acc.z, acc.w);
        ((uint2*)yp)[jg] = cv.u2;
    }
}

// ---------------- pull-style GCN aggregation ----------------
// One wave per node, both channels. Lane l covers flat half-offsets [2l,2l+1]
// of the node's 128-half block -> one 4 B gather per neighbor covers both
// channels (256 B/wave, coalesced). Buckets padded to multiples of 16 ->
// branch-free inner loop with 16 independent gathers in flight.

__global__ __launch_bounds__(256) void k_prop(const __half* __restrict__ hw,
                                              const float* __restrict__ bias,
                                              const float* __restrict__ self_norm,
                                              const int* __restrict__ cnt,
                                              const int2* __restrict__ pairs,
                                              float* __restrict__ agg) {
    int t = threadIdx.x;
    int lane = t & 63;
    int n = __builtin_amdgcn_readfirstlane(blockIdx.x * 4 + (t >> 6));
    if (n >= NNODES) return;

    int f = lane * 2;            // flat half-offset in [0,128), even
    int feat = f & 63;

    float2 bv = *(const float2*)(bias + feat);
    float sn = self_norm[n];
    float2 self = __half22float2(*(const __half2*)(hw + (size_t)n * 128 + f));
    float acc0 = bv.x + sn * self.x;
    float acc1 = bv.y + sn * self.y;

    int cn = cnt[n]; if (cn > CAP) cn = CAP;
    int c16 = (cn + 15) & ~15;
    const int2* pp = pairs + (size_t)n * CAP;

    for (int p = 0; p < c16; p += 16) {
        const int2* q = pp + p;
        int2 e[16];
        #pragma unroll
        for (int i = 0; i < 16; i++) e[i] = q[i];
        float2 h[16];
        #pragma unroll
        for (int i = 0; i < 16; i++)
            h[i] = __half22float2(*(const __half2*)(hw + (size_t)e[i].x * 128 + f));
        #pragma unroll
        for (int i = 0; i < 16; i++) {
            float w = __int_as_float(e[i].y);
            acc0 += w * h[i].x;
            acc1 += w * h[i].y;
        }
    }

    *(float2*)(agg + (size_t)n * 128 + f) = make_float2(acc0, acc1);
}

// ---------------- GraphNorm stats (sum, sumsq per column) ----------------

__global__ __launch_bounds__(256) void k_stats(const float* __restrict__ agg,
                                               float* __restrict__ stats) {
    int t = threadIdx.x;
    int col  = t & 127;
    int half = t >> 7;
    float s = 0.f, s2 = 0.f;
    for (int r = blockIdx.x * 2 + half; r < NNODES; r += gridDim.x * 2) {
        float v = agg[r * 128 + col];
        s += v; s2 += v * v;
    }
    atomicAdd(&stats[col], s);
    atomicAdd(&stats[128 + col], s2);
}

__global__ void k_coef(float* stats, const float* __restrict__ gn_w,
                       const float* __restrict__ gn_b, const float* __restrict__ gn_ms) {
    int col = threadIdx.x;  // 128
    float inv_n = 1.0f / (float)NNODES;
    float mean = stats[col] * inv_n;
    float eh2  = stats[128 + col] * inv_n;
    int f = col & 63;
    float ms = gn_ms[f];
    float var = eh2 - 2.0f * ms * mean * mean + ms * ms * mean * mean;
    float A = gn_w[f] * rsqrtf(var + 1e-5f);
    stats[256 + col] = A;
    stats[384 + col] = gn_b[f] - A * ms * mean;
}

// ---------------- fused subgraph pooling + MLP head ----------------

__global__ __launch_bounds__(128) void k_head(const float* __restrict__ agg,
                                              const int* __restrict__ subg,
                                              const float* __restrict__ mW1,
                                              const float* __restrict__ mb1,
                                              const float* __restrict__ mW2,
                                              const float* __restrict__ mb2,
                                              float* __restrict__ out) {
    __shared__ float pl[128];
    __shared__ float red[128];
    int s = blockIdx.x, t = threadIdx.x;
    int j = t & 63, half = t >> 6;
    const int* idx = subg + s * 64;
    float acc = 0.f;
    for (int m = half * 32; m < half * 32 + 32; m++) {
        int n = idx[m];
        acc += 0.5f * (agg[(size_t)n * 128 + j] + agg[(size_t)n * 128 + 64 + j]);
    }
    pl[half * 64 + j] = acc;
    __syncthreads();
    if (t < 64) pl[t] += pl[64 + t];
    __syncthreads();
    float h = mb1[t];
    #pragma unroll
    for (int k = 0; k < 64; k++) h += pl[k] * mW1[k * 128 + t];
    h = fmaxf(h, 0.0f);
    red[t] = h * mW2[t];
    __syncthreads();
    for (int off = 64; off > 0; off >>= 1) {
        if (t < off) red[t] += red[t + off];
        __syncthreads();
    }
    if (t == 0) out[s] = red[0] + mb2[0];
}

// ---------------- launcher ----------------

extern "C" void kernel_launch(void* const* d_in, const int* in_sizes, int n_in,
                              void* d_out, int out_size, void* d_ws, size_t ws_size,
                              hipStream_t stream) {
    const float* x     = (const float*)d_in[0];
    const int*   ei    = (const int*)d_in[1];
    const float* ew    = (const float*)d_in[2];
    const int*   subg  = (const int*)d_in[3];
    const float* W1    = (const float*)d_in[4];
    const float* b1    = (const float*)d_in[5];
    const float* gn_w  = (const float*)d_in[6];
    const float* gn_b  = (const float*)d_in[7];
    const float* gn_ms = (const float*)d_in[8];
    const float* W2    = (const float*)d_in[9];
    const float* b2    = (const float*)d_in[10];
    const float* mW1   = (const float*)d_in[11];
    const float* mb1   = (const float*)d_in[12];
    const float* mW2   = (const float*)d_in[13];
    const float* mb2   = (const float*)d_in[14];
    float* out = (float*)d_out;

    char* w = (char*)d_ws;
    size_t off = 0;
    auto alloc = [&](size_t bytes) {
        void* p = w + off;
        off = (off + bytes + 255) & ~(size_t)255;
        return p;
    };
    float*  dinv      = (float*) alloc((size_t)NNODES * 4);        // deg -> dinv in place
    float*  self_norm = (float*) alloc((size_t)NNODES * 4);
    int*    cnt       = (int*)   alloc((size_t)NNODES * 4);
    int2*   pairs     = (int2*)  alloc((size_t)NNODES * CAP * 8);  // 51.2 MB
    __half* hw        = (__half*)alloc((size_t)NNODES * 128 * 2);  // 25.6 MB
    float*  agg       = (float*) alloc((size_t)NNODES * 128 * 4);  // 51.2 MB
    float*  stats     = (float*) alloc(512 * 4);
    (void)self_norm;

    const int* src = ei;
    const int* dst = ei + NEDGES;

    // zero deg/self_norm/cnt (contiguous span) and stats
    size_t span = (size_t)((char*)cnt - (char*)dinv) + (size_t)NNODES * 4;
    hipMemsetAsync(dinv, 0, span, stream);
    hipMemsetAsync(stats, 0, 512 * 4, stream);

    // preprocessing: one edge pass, then normalize+pad buckets
    k_fill<<<(NEDGES + 255) / 256, 256, 0, stream>>>(src, dst, ew, dinv, cnt, pairs);
    k_dinv<<<(NNODES + 255) / 256, 256, 0, stream>>>(dinv, self_norm);
    k_norm<<<25000, 256, 0, stream>>>(dinv, cnt, pairs);

    // layer 1
    k_gemm<false><<<782, 256, 0, stream>>>(x, W1, hw, nullptr, nullptr);
    k_prop<<<25000, 256, 0, stream>>>(hw, b1, self_norm, cnt, pairs, agg);

    // GraphNorm coefficients
    k_stats<<<256, 256, 0, stream>>>(agg, stats);
    k_coef<<<1, 128, 0, stream>>>(stats, gn_w, gn_b, gn_ms);

    // layer 2 (GraphNorm+ReLU fused into GEMM2 input)
    k_gemm<true><<<782, 256, 0, stream>>>(agg, W2, hw, stats + 256, stats + 384);
    k_prop<<<25000, 256, 0, stream>>>(hw, b2, self_norm, cnt, pairs, agg);

    // fused pooling + MLP head
    k_head<<<NSUB, 128, 0, stream>>>(agg, subg, mW1, mb1, mW2, mb2, out);
}